// Round 9
// baseline (1326.710 us; speedup 1.0000x reference)
//
#include <hip/hip_runtime.h>
#include <hip/hip_bf16.h>

#define B_ 32
#define S_ 512
#define IN_ 19
#define DE_ 256
#define DD_ 128
#define HE_ 8
#define HD_ 4
#define LE_ 6
#define LD_ 2
#define FE_ 1024
#define FD_ 512
#define DH_ 32

typedef __attribute__((ext_vector_type(8))) short short8;
typedef __attribute__((ext_vector_type(4))) float f32x4;

__device__ __forceinline__ short f2bf(float f) {
    union { float f; unsigned u; } x; x.f = f;
    unsigned r = x.u + 0x7fff + ((x.u >> 16) & 1);
    return (short)(r >> 16);
}
__device__ __forceinline__ float bf2f(short s) {
    union { unsigned u; float f; } x; x.u = ((unsigned)(unsigned short)s) << 16;
    return x.f;
}

#define GLL16(g, l) __builtin_amdgcn_global_load_lds( \
    (const __attribute__((address_space(1))) void*)(g), \
    (__attribute__((address_space(3))) void*)(l), 16, 0, 0)

// (1/sqrt(32)) * log2(e), folded into Q at the QKV epilogue
#define QSCALE 0.2550653169f

// ---------------------------------------------------------------------------
// weight fp32 -> bf16 conversion
// ---------------------------------------------------------------------------
#define NCONV 9
struct ConvTab {
    const float* src[NCONV];
    short* dst[NCONV];
    int len[NCONV];
};
__global__ __launch_bounds__(256) void conv_kernel(ConvTab tab, int total) {
    int i = blockIdx.x * 256 + threadIdx.x;
    if (i >= total) return;
    int j = i;
    for (int e = 0; e < NCONV; ++e) {
        if (j < tab.len[e]) { tab.dst[e][j] = f2bf(tab.src[e][j]); return; }
        j -= tab.len[e];
    }
}

// ---------------------------------------------------------------------------
// plan: packed dual scan (visible-count + am-length), one 512-thr block/batch
// ---------------------------------------------------------------------------
__global__ __launch_bounds__(S_) void plan_kernel(
    const int* __restrict__ am, const int* __restrict__ pm,
    int* __restrict__ counts, int* __restrict__ lengths, int* __restrict__ order,
    int* __restrict__ visible, int* __restrict__ idx) {
    int b = blockIdx.x, s = threadIdx.x;
    __shared__ int sc[S_];
    int a = (am[b * S_ + s] != 0);
    int v = a && (pm[b * S_ + s] == 0);
    visible[b * S_ + s] = v;
    sc[s] = v | (a << 16);
    __syncthreads();
#pragma unroll
    for (int off = 1; off < S_; off <<= 1) {
        int t = (s >= off) ? sc[s - off] : 0;
        __syncthreads();
        sc[s] += t;
        __syncthreads();
    }
    int incl = sc[s] & 0xffff;
    int tot = sc[S_ - 1];
    int total = tot & 0xffff;
    if (s == 0) { counts[b] = total; lengths[b] = tot >> 16; }
    idx[b * S_ + s] = (incl > 0) ? incl - 1 : 0;
    if (v) order[b * S_ + incl - 1] = s;
    else   order[b * S_ + total + (s - incl)] = s;
}

// ---------------------------------------------------------------------------
// encoder embed
// ---------------------------------------------------------------------------
__global__ __launch_bounds__(DE_) void enc_embed_kernel(
    const float* __restrict__ ev, const float* __restrict__ w, const float* __restrict__ bias,
    const int* __restrict__ counts, const int* __restrict__ order, short* __restrict__ out) {
    int bs = blockIdx.x;
    int b = bs / S_, s = bs % S_;
    int d = threadIdx.x;
    __shared__ float e[IN_];
    bool padded = (s >= counts[b]);
    int src = order[bs];
    if (threadIdx.x < IN_)
        e[threadIdx.x] = padded ? 0.f : ev[(size_t)(b * S_ + src) * IN_ + threadIdx.x];
    __syncthreads();
    float acc = bias[d];
#pragma unroll
    for (int i = 0; i < IN_; ++i) acc += e[i] * w[d * IN_ + i];
    out[(size_t)bs * DE_ + d] = padded ? f2bf(0.f) : f2bf(acc);
}

// ---------------------------------------------------------------------------
// Plain MFMA bf16 GEMM (qkv / f1 / e2d): 128x128 tile, BK=32.
// ---------------------------------------------------------------------------
template <bool RELU, bool QKV>
__global__ __launch_bounds__(256) void gemm_mfma(
    const short* __restrict__ A, const short* __restrict__ Wt, const float* __restrict__ bias,
    short* __restrict__ C, int M, int N, int K,
    short* __restrict__ qb, short* __restrict__ kb, short* __restrict__ vtb, int H, int D,
    const int* __restrict__ live) {
    int bm = blockIdx.y * 128, bn = blockIdx.x * 128;
    if (live && (bm & (S_ - 1)) >= live[bm >> 9]) return;
    __shared__ short As[128][32];
    __shared__ short Bs[128][32];
    int t = threadIdx.x;
    int wave = t >> 6, lane = t & 63;
    int wm = (wave >> 1) * 64, wn = (wave & 1) * 64;
    int c = lane & 15, quad = lane >> 4;
    f32x4 acc[4][4];
#pragma unroll
    for (int i = 0; i < 4; ++i)
#pragma unroll
        for (int j = 0; j < 4; ++j) acc[i][j] = (f32x4){0.f, 0.f, 0.f, 0.f};

    const short* gA = A + (size_t)(bm + wave * 32 + (lane >> 2)) * K + (lane & 3) * 8;
    const short* gB = Wt + (size_t)(bn + wave * 32 + (lane >> 2)) * K + (lane & 3) * 8;

    for (int k0 = 0; k0 < K; k0 += 32) {
        GLL16(gA + k0, &As[wave * 32][0]);
        GLL16(gA + 16 * K + k0, &As[wave * 32 + 16][0]);
        GLL16(gB + k0, &Bs[wave * 32][0]);
        GLL16(gB + 16 * K + k0, &Bs[wave * 32 + 16][0]);
        __syncthreads();
        short8 a[4], b[4];
#pragma unroll
        for (int i = 0; i < 4; ++i) a[i] = *(const short8*)&As[wm + i * 16 + c][quad * 8];
#pragma unroll
        for (int j = 0; j < 4; ++j) b[j] = *(const short8*)&Bs[wn + j * 16 + c][quad * 8];
#pragma unroll
        for (int i = 0; i < 4; ++i)
#pragma unroll
            for (int j = 0; j < 4; ++j)
                acc[i][j] = __builtin_amdgcn_mfma_f32_16x16x32_bf16(a[i], b[j], acc[i][j], 0, 0, 0);
        __syncthreads();
    }
#pragma unroll
    for (int mt = 0; mt < 4; ++mt)
#pragma unroll
        for (int nt = 0; nt < 4; ++nt)
#pragma unroll
            for (int r = 0; r < 4; ++r) {
                int R = bm + wm + mt * 16 + quad * 4 + r;
                int Ncol = bn + wn + nt * 16 + c;
                float v = acc[mt][nt][r] + (bias ? bias[Ncol] : 0.f);
                if (RELU) v = fmaxf(v, 0.f);
                if (!QKV) {
                    C[(size_t)R * N + Ncol] = f2bf(v);
                } else {
                    int s = R & (S_ - 1), b2 = R >> 9;
                    if (Ncol < D) {
                        int h = Ncol >> 5, d = Ncol & 31;
                        qb[(((size_t)b2 * H + h) * S_ + s) * DH_ + d] = f2bf(v * QSCALE);
                    } else if (Ncol < 2 * D) {
                        int n2 = Ncol - D, h = n2 >> 5, d = n2 & 31;
                        kb[(((size_t)b2 * H + h) * S_ + s) * DH_ + d] = f2bf(v);
                    } else {
                        int n2 = Ncol - 2 * D, h = n2 >> 5, d = n2 & 31;
                        vtb[(((size_t)b2 * H + h) * DH_ + d) * S_ + s] = f2bf(v);
                    }
                }
            }
}

// ---------------------------------------------------------------------------
// Fused GEMM + residual + LayerNorm (+ optional head). Block owns the FULL
// output row: 128 rows x BNT cols (BNT = N). Row stats cross the 2 n-waves
// via LDS partials. HEAD: fuse the two 1-wide output heads, write d_out.
//   out_row = LN(X_row + A_row @ W^T + bias) * g + be
// ---------------------------------------------------------------------------
template <int BNT, bool HEAD>
__global__ __launch_bounds__(256) void gemm_ln(
    const short* __restrict__ A, const short* __restrict__ Wt, const float* __restrict__ bias,
    const short* __restrict__ X, short* __restrict__ OutX,
    const float* __restrict__ g, const float* __restrict__ be,
    int K, const int* __restrict__ live,
    const float* __restrict__ qw, const float* __restrict__ qb2,
    const float* __restrict__ dw, const float* __restrict__ db2,
    float* __restrict__ outh) {
    constexpr int NT = BNT / 32;        // n-tiles per wave
    constexpr int RB = BNT / 4;         // B rows staged per wave
    int bm = blockIdx.x * 128;
    if (live && (bm & (S_ - 1)) >= live[bm >> 9]) return;
    __shared__ short As[128][32];
    __shared__ short Bs[BNT][32];
    __shared__ float red[128][2][2];
    __shared__ float hred[128][2][2];
    int t = threadIdx.x;
    int wave = t >> 6, lane = t & 63;
    int wm = (wave >> 1) * 64, wn = (wave & 1) * (BNT / 2);
    int wnIdx = wave & 1;
    int c = lane & 15, quad = lane >> 4;
    f32x4 acc[4][NT];
#pragma unroll
    for (int i = 0; i < 4; ++i)
#pragma unroll
        for (int j = 0; j < NT; ++j) acc[i][j] = (f32x4){0.f, 0.f, 0.f, 0.f};

    const short* gA = A + (size_t)(bm + wave * 32 + (lane >> 2)) * K + (lane & 3) * 8;
    const short* gB = Wt + (size_t)(wave * RB + (lane >> 2)) * K + (lane & 3) * 8;

    for (int k0 = 0; k0 < K; k0 += 32) {
        GLL16(gA + k0, &As[wave * 32][0]);
        GLL16(gA + 16 * K + k0, &As[wave * 32 + 16][0]);
#pragma unroll
        for (int i = 0; i < RB / 16; ++i)
            GLL16(gB + (size_t)i * 16 * K + k0, &Bs[wave * RB + i * 16][0]);
        __syncthreads();
        short8 a[4], b[NT];
#pragma unroll
        for (int i = 0; i < 4; ++i) a[i] = *(const short8*)&As[wm + i * 16 + c][quad * 8];
#pragma unroll
        for (int j = 0; j < NT; ++j) b[j] = *(const short8*)&Bs[wn + j * 16 + c][quad * 8];
#pragma unroll
        for (int i = 0; i < 4; ++i)
#pragma unroll
            for (int j = 0; j < NT; ++j)
                acc[i][j] = __builtin_amdgcn_mfma_f32_16x16x32_bf16(a[i], b[j], acc[i][j], 0, 0, 0);
        __syncthreads();
    }
    float bv[NT];
#pragma unroll
    for (int j = 0; j < NT; ++j) bv[j] = bias[wn + j * 16 + c];
    // phase 1: residual add + per-row partial stats
#pragma unroll
    for (int mt = 0; mt < 4; ++mt)
#pragma unroll
        for (int r = 0; r < 4; ++r) {
            int row = wm + mt * 16 + quad * 4 + r;
            float sum = 0.f, sq = 0.f;
#pragma unroll
            for (int nt = 0; nt < NT; ++nt) {
                int col = wn + nt * 16 + c;
                float v = acc[mt][nt][r] + bv[nt] + bf2f(X[(size_t)(bm + row) * BNT + col]);
                acc[mt][nt][r] = v;
                sum += v; sq += v * v;
            }
            sum += __shfl_xor(sum, 1); sq += __shfl_xor(sq, 1);
            sum += __shfl_xor(sum, 2); sq += __shfl_xor(sq, 2);
            sum += __shfl_xor(sum, 4); sq += __shfl_xor(sq, 4);
            sum += __shfl_xor(sum, 8); sq += __shfl_xor(sq, 8);
            if (c == 0) { red[row][wnIdx][0] = sum; red[row][wnIdx][1] = sq; }
        }
    __syncthreads();
    // phase 2: normalize + write (or head dots)
#pragma unroll
    for (int mt = 0; mt < 4; ++mt)
#pragma unroll
        for (int r = 0; r < 4; ++r) {
            int row = wm + mt * 16 + quad * 4 + r;
            float sum = red[row][0][0] + red[row][1][0];
            float sq  = red[row][0][1] + red[row][1][1];
            float m = sum / BNT;
            float var = sq / BNT - m * m;
            float rstd = rsqrtf(var + 1e-5f);
            float phq = 0.f, phd = 0.f;
#pragma unroll
            for (int nt = 0; nt < NT; ++nt) {
                int col = wn + nt * 16 + c;
                float o = (acc[mt][nt][r] - m) * rstd * g[col] + be[col];
                if (!HEAD) OutX[(size_t)(bm + row) * BNT + col] = f2bf(o);
                else { phq += o * qw[col]; phd += o * dw[col]; }
            }
            if (HEAD) {
                phq += __shfl_xor(phq, 1); phd += __shfl_xor(phd, 1);
                phq += __shfl_xor(phq, 2); phd += __shfl_xor(phd, 2);
                phq += __shfl_xor(phq, 4); phd += __shfl_xor(phd, 4);
                phq += __shfl_xor(phq, 8); phd += __shfl_xor(phd, 8);
                if (c == 0) { hred[row][wnIdx][0] = phq; hred[row][wnIdx][1] = phd; }
            }
        }
    if (HEAD) {
        __syncthreads();
        if (t < 128) {
            outh[(size_t)(bm + t) * 2 + 0] = hred[t][0][0] + hred[t][1][0] + qb2[0];
            outh[(size_t)(bm + t) * 2 + 1] = hred[t][0][1] + hred[t][1][1] + db2[0];
        }
    }
}

// ---------------------------------------------------------------------------
// Flash MFMA attention, prefix-mask chunk skipping; optional q-tile skipping.
// ---------------------------------------------------------------------------
__global__ __launch_bounds__(256) void attn_flash(
    const short* __restrict__ qb, const short* __restrict__ kb, const short* __restrict__ vtb,
    const int* __restrict__ limit_arr, const int* __restrict__ qlim,
    short* __restrict__ o, int H, int D) {
    int b = blockIdx.z, h = blockIdx.y;
    if (qlim && (int)(blockIdx.x * 64) >= qlim[b]) return;
    int wave = threadIdx.x >> 6, lane = threadIdx.x & 63;
    int q0 = blockIdx.x * 64 + wave * 16;
    int c = lane & 15, quad = lane >> 4;
    size_t bh = (size_t)b * H + h;
    __shared__ short PtAll[4][16][132];
    short (*Pt)[132] = PtAll[wave];

    f32x4 zero = (f32x4){0.f, 0.f, 0.f, 0.f};
    short8 aq = *(const short8*)&qb[(bh * S_ + q0 + c) * DH_ + quad * 8];
    const short* kbase = kb + bh * S_ * DH_;
    const short* vbase = vtb + bh * DH_ * S_;

    int limit = limit_arr[b];
    int nchunks = (limit + 127) >> 7;

    float lrow[4] = {0.f, 0.f, 0.f, 0.f};
    f32x4 o0 = zero, o1 = zero;

    for (int kc = 0; kc < nchunks; ++kc) {
        f32x4 s[8];
#pragma unroll
        for (int nt = 0; nt < 8; ++nt) {
            short8 bk = *(const short8*)&kbase[(size_t)(kc * 128 + nt * 16 + c) * DH_ + quad * 8];
            s[nt] = __builtin_amdgcn_mfma_f32_16x16x32_bf16(aq, bk, zero, 0, 0, 0);
        }
#pragma unroll
        for (int nt = 0; nt < 8; ++nt) {
            bool ok = (kc * 128 + nt * 16 + c) < limit;
#pragma unroll
            for (int r = 0; r < 4; ++r) {
                float p = ok ? exp2f(s[nt][r]) : 0.f;
                s[nt][r] = p;
                lrow[r] += p;
            }
        }
#pragma unroll
        for (int nt = 0; nt < 8; ++nt)
#pragma unroll
            for (int r = 0; r < 4; ++r)
                Pt[quad * 4 + r][nt * 16 + c] = f2bf(s[nt][r]);
#pragma unroll
        for (int kk = 0; kk < 4; ++kk) {
            short8 ap = *(const short8*)&Pt[c][kk * 32 + quad * 8];
            short8 b0 = *(const short8*)&vbase[(size_t)c * S_ + kc * 128 + kk * 32 + quad * 8];
            short8 b1 = *(const short8*)&vbase[(size_t)(16 + c) * S_ + kc * 128 + kk * 32 + quad * 8];
            o0 = __builtin_amdgcn_mfma_f32_16x16x32_bf16(ap, b0, o0, 0, 0, 0);
            o1 = __builtin_amdgcn_mfma_f32_16x16x32_bf16(ap, b1, o1, 0, 0, 0);
        }
    }
#pragma unroll
    for (int r = 0; r < 4; ++r) {
        float l = lrow[r];
        l += __shfl_xor(l, 1);
        l += __shfl_xor(l, 2);
        l += __shfl_xor(l, 4);
        l += __shfl_xor(l, 8);
        float inv = 1.f / l;
        int row = quad * 4 + r;
        size_t base = (size_t)(b * S_ + q0 + row) * D + h * DH_;
        o[base + c] = f2bf(o0[r] * inv);
        o[base + 16 + c] = f2bf(o1[r] * inv);
    }
}

// ---------------------------------------------------------------------------
// decoder embed
// ---------------------------------------------------------------------------
__global__ __launch_bounds__(DD_) void dec_embed_kernel(
    const short* __restrict__ dec_vis, const float* __restrict__ mask_token,
    const int* __restrict__ visible, const int* __restrict__ idx, short* __restrict__ out) {
    int bs = blockIdx.x, d = threadIdx.x;
    int b = bs / S_;
    short val = visible[bs] ? dec_vis[(size_t)(b * S_ + idx[bs]) * DD_ + d]
                            : f2bf(mask_token[d]);
    out[(size_t)bs * DD_ + d] = val;
}

// ---------------------------------------------------------------------------
extern "C" void kernel_launch(void* const* d_in, const int* in_sizes, int n_in,
                              void* d_out, int out_size, void* d_ws, size_t ws_size,
                              hipStream_t stream) {
    const float* ev      = (const float*)d_in[0];
    const int*  am       = (const int*)d_in[1];
    const int*  pm       = (const int*)d_in[2];
    const float* w_in    = (const float*)d_in[3];
    const float* b_in    = (const float*)d_in[4];
    const float* eqkv_w  = (const float*)d_in[5];
    const float* eqkv_b  = (const float*)d_in[6];
    const float* eout_w  = (const float*)d_in[7];
    const float* eout_b  = (const float*)d_in[8];
    const float* ef1_w   = (const float*)d_in[9];
    const float* ef1_b   = (const float*)d_in[10];
    const float* ef2_w   = (const float*)d_in[11];
    const float* ef2_b   = (const float*)d_in[12];
    const float* eg1     = (const float*)d_in[13];
    const float* eb1     = (const float*)d_in[14];
    const float* eg2     = (const float*)d_in[15];
    const float* eb2     = (const float*)d_in[16];
    const float* mask_tok= (const float*)d_in[17];
    const float* e2d_w   = (const float*)d_in[18];
    const float* dqkv_w  = (const float*)d_in[19];
    const float* dqkv_b  = (const float*)d_in[20];
    const float* dout_w  = (const float*)d_in[21];
    const float* dout_b  = (const float*)d_in[22];
    const float* df1_w   = (const float*)d_in[23];
    const float* df1_b   = (const float*)d_in[24];
    const float* df2_w   = (const float*)d_in[25];
    const float* df2_b   = (const float*)d_in[26];
    const float* dg1     = (const float*)d_in[27];
    const float* db1     = (const float*)d_in[28];
    const float* dg2     = (const float*)d_in[29];
    const float* db2     = (const float*)d_in[30];
    const float* qh_w    = (const float*)d_in[31];
    const float* qh_b    = (const float*)d_in[32];
    const float* dth_w   = (const float*)d_in[33];
    const float* dth_b   = (const float*)d_in[34];
    float* out = (float*)d_out;

    const int BS = B_ * S_;
    char* ws = (char*)d_ws;
    int* counts  = (int*)ws;
    int* lengths = counts + 32;
    int* order   = lengths + 32;
    int* visible = order + BS;
    int* idx     = visible + BS;

    short* wb = (short*)(ws + 256 * 1024);
    const int L_eqkv = LE_ * 3 * DE_ * DE_;
    const int L_eout = LE_ * DE_ * DE_;
    const int L_ef1  = LE_ * FE_ * DE_;
    const int L_ef2  = LE_ * DE_ * FE_;
    const int L_e2d  = DD_ * DE_;
    const int L_dqkv = LD_ * 3 * DD_ * DD_;
    const int L_dout = LD_ * DD_ * DD_;
    const int L_df1  = LD_ * FD_ * DD_;
    const int L_df2  = LD_ * DD_ * FD_;
    short* w_eqkv = wb;
    short* w_eout = w_eqkv + L_eqkv;
    short* w_ef1  = w_eout + L_eout;
    short* w_ef2  = w_ef1 + L_ef1;
    short* w_e2d  = w_ef2 + L_ef2;
    short* w_dqkv = w_e2d + L_e2d;
    short* w_dout = w_dqkv + L_dqkv;
    short* w_df1  = w_dout + L_dout;
    short* w_df2  = w_df1 + L_df1;
    const int convTotal = L_eqkv + L_eout + L_ef1 + L_ef2 + L_e2d + L_dqkv + L_dout + L_df1 + L_df2;

    short* bx    = (short*)(ws + 12 * 1024 * 1024);
    short* qbuf  = bx   + (size_t)BS * DE_;
    short* kbuf  = qbuf + (size_t)B_ * HE_ * S_ * DH_;
    short* vtbuf = kbuf + (size_t)B_ * HE_ * S_ * DH_;
    short* battn = vtbuf + (size_t)B_ * HE_ * S_ * DH_;
    short* bt    = battn + (size_t)BS * DE_;
    short* hid   = bt + (size_t)BS * DE_;

    ConvTab tab;
    tab.src[0] = eqkv_w; tab.dst[0] = w_eqkv; tab.len[0] = L_eqkv;
    tab.src[1] = eout_w; tab.dst[1] = w_eout; tab.len[1] = L_eout;
    tab.src[2] = ef1_w;  tab.dst[2] = w_ef1;  tab.len[2] = L_ef1;
    tab.src[3] = ef2_w;  tab.dst[3] = w_ef2;  tab.len[3] = L_ef2;
    tab.src[4] = e2d_w;  tab.dst[4] = w_e2d;  tab.len[4] = L_e2d;
    tab.src[5] = dqkv_w; tab.dst[5] = w_dqkv; tab.len[5] = L_dqkv;
    tab.src[6] = dout_w; tab.dst[6] = w_dout; tab.len[6] = L_dout;
    tab.src[7] = df1_w;  tab.dst[7] = w_df1;  tab.len[7] = L_df1;
    tab.src[8] = df2_w;  tab.dst[8] = w_df2;  tab.len[8] = L_df2;
    conv_kernel<<<(convTotal + 255) / 256, 256, 0, stream>>>(tab, convTotal);

    plan_kernel<<<B_, S_, 0, stream>>>(am, pm, counts, lengths, order, visible, idx);
    enc_embed_kernel<<<BS, DE_, 0, stream>>>(ev, w_in, b_in, counts, order, bx);

    // -------------------- encoder: 5 kernels/layer --------------------
    for (int l = 0; l < LE_; ++l) {
        gemm_mfma<false, true><<<dim3(3 * DE_ / 128, BS / 128), 256, 0, stream>>>(
            bx, w_eqkv + (size_t)l * 3 * DE_ * DE_, eqkv_b + (size_t)l * 3 * DE_,
            nullptr, BS, 3 * DE_, DE_, qbuf, kbuf, vtbuf, HE_, DE_, counts);
        attn_flash<<<dim3(S_ / 64, HE_, B_), 256, 0, stream>>>(
            qbuf, kbuf, vtbuf, counts, counts, battn, HE_, DE_);
        gemm_ln<DE_, false><<<BS / 128, 256, 0, stream>>>(
            battn, w_eout + (size_t)l * DE_ * DE_, eout_b + (size_t)l * DE_,
            bx, bx, eg1 + (size_t)l * DE_, eb1 + (size_t)l * DE_, DE_, counts,
            nullptr, nullptr, nullptr, nullptr, nullptr);
        gemm_mfma<true, false><<<dim3(FE_ / 128, BS / 128), 256, 0, stream>>>(
            bx, w_ef1 + (size_t)l * FE_ * DE_, ef1_b + (size_t)l * FE_,
            hid, BS, FE_, DE_, nullptr, nullptr, nullptr, 0, 0, counts);
        gemm_ln<DE_, false><<<BS / 128, 256, 0, stream>>>(
            hid, w_ef2 + (size_t)l * DE_ * FE_, ef2_b + (size_t)l * DE_,
            bx, bx, eg2 + (size_t)l * DE_, eb2 + (size_t)l * DE_, FE_, counts,
            nullptr, nullptr, nullptr, nullptr, nullptr);
    }

    // -------------------- enc -> dec --------------------
    gemm_mfma<false, false><<<dim3(DD_ / 128, BS / 128), 256, 0, stream>>>(
        bx, w_e2d, nullptr, bt, BS, DD_, DE_, nullptr, nullptr, nullptr, 0, 0, counts);
    dec_embed_kernel<<<BS, DD_, 0, stream>>>(bt, mask_tok, visible, idx, bx);

    // -------------------- decoder: 5 kernels/layer, head fused in last ----
    for (int l = 0; l < LD_; ++l) {
        gemm_mfma<false, true><<<dim3(3 * DD_ / 128, BS / 128), 256, 0, stream>>>(
            bx, w_dqkv + (size_t)l * 3 * DD_ * DD_, dqkv_b + (size_t)l * 3 * DD_, nullptr,
            BS, 3 * DD_, DD_, qbuf, kbuf, vtbuf, HD_, DD_, nullptr);
        attn_flash<<<dim3(S_ / 64, HD_, B_), 256, 0, stream>>>(
            qbuf, kbuf, vtbuf, lengths, nullptr, battn, HD_, DD_);
        gemm_ln<DD_, false><<<BS / 128, 256, 0, stream>>>(
            battn, w_dout + (size_t)l * DD_ * DD_, dout_b + (size_t)l * DD_,
            bx, bx, dg1 + (size_t)l * DD_, db1 + (size_t)l * DD_, DD_, nullptr,
            nullptr, nullptr, nullptr, nullptr, nullptr);
        gemm_mfma<true, false><<<dim3(FD_ / 128, BS / 128), 256, 0, stream>>>(
            bx, w_df1 + (size_t)l * FD_ * DD_, df1_b + (size_t)l * FD_,
            hid, BS, FD_, DD_, nullptr, nullptr, nullptr, 0, 0, nullptr);
        if (l < LD_ - 1) {
            gemm_ln<DD_, false><<<BS / 128, 256, 0, stream>>>(
                hid, w_df2 + (size_t)l * DD_ * FD_, df2_b + (size_t)l * DD_,
                bx, bx, dg2 + (size_t)l * DD_, db2 + (size_t)l * DD_, FD_, nullptr,
                nullptr, nullptr, nullptr, nullptr, nullptr);
        } else {
            gemm_ln<DD_, true><<<BS / 128, 256, 0, stream>>>(
                hid, w_df2 + (size_t)l * DD_ * FD_, df2_b + (size_t)l * DD_,
                bx, bx, dg2 + (size_t)l * DD_, db2 + (size_t)l * DD_, FD_, nullptr,
                qh_w, qh_b, dth_w, dth_b, out);
        }
    }
}